// Round 12
// baseline (31.385 us; speedup 1.0000x reference)
//
#include <hip/hip_runtime.h>
#include <cstdint>
#include <cstddef>

// out[b,c,h,w] = sum_nb x[b, rp[c][nb], h, w] * 2^nb ; x in {0.0,1.0} exactly.
//
// Two-pass: pass 1 packs the 64 bit-planes into a u64 mask per pixel
// (2 MiB intermediate in d_ws, stays in L2/L3); pass 2 expands masks to the
// 64 output channels. Each pass is a nearly-unidirectional HBM stream.
constexpr int Bn = 16;
constexpr int TBn = 64;
constexpr int Cn = 64;
constexpr int HW = 128 * 128;                // 16384 pixels per (b, plane)
constexpr int TOTAL_PIX = Bn * HW;           // 262144
constexpr int GROUPS = TOTAL_PIX / 4;        // 65536 4-pixel groups
constexpr int PIX_PER_BLOCK = 256;
constexpr int BLOCKS = TOTAL_PIX / PIX_PER_BLOCK;   // 1024 (both passes)

typedef float v4f __attribute__((ext_vector_type(4)));

// ---- Pass 1: x -> per-pixel quarter-masks. ----
// Thread (g, q): 4 pixels (f4 group g), planes q*16..q*16+15.
// Writes one u64 = the 4 pixels' 16-bit quarter-masks, at ws[q][group]
// (quarter-major so wave stores are 512 B contiguous).
__global__ __launch_bounds__(256) void rp_pack_p1(
    const float* __restrict__ x,
    uint64_t* __restrict__ ws)
{
    const int b = blockIdx.x >> 6;              // 64 blocks per image
    const int pix0 = (blockIdx.x & 63) << 8;    // 256 pixels per block
    const int g = threadIdx.x & 63;             // f4 group within block
    const int q = threadIdx.x >> 6;             // plane quarter 0..3

    // x is exactly 0.0f/1.0f: bit 23 of the encoding == (v == 1.0f).
    const float* xb = x + (size_t)b * TBn * HW + (size_t)(q * 16) * HW
                        + pix0 + g * 4;

    uint32_t p0 = 0, p1 = 0, p2 = 0, p3 = 0;
    #pragma unroll
    for (int i = 0; i < 16; ++i) {
        const v4f v = *reinterpret_cast<const v4f*>(xb + (size_t)i * HW);
        p0 |= ((__float_as_uint(v.x) >> 23) & 1u) << i;
        p1 |= ((__float_as_uint(v.y) >> 23) & 1u) << i;
        p2 |= ((__float_as_uint(v.z) >> 23) & 1u) << i;
        p3 |= ((__float_as_uint(v.w) >> 23) & 1u) << i;
    }

    const uint64_t v64 = (uint64_t)(unsigned short)p0
                       | ((uint64_t)(unsigned short)p1 << 16)
                       | ((uint64_t)(unsigned short)p2 << 32)
                       | ((uint64_t)(unsigned short)p3 << 48);
    // global group index: blockIdx.x*64 + g
    ws[(size_t)q * GROUPS + blockIdx.x * 64 + g] = v64;
}

// ---- Pass 2: quarter-masks -> 64 output channels. ----
// Thread (g, cq): 4 pixels of group g, channels cq*16..cq*16+15.
__global__ __launch_bounds__(256) void rp_pack_p2(
    const uint64_t* __restrict__ ws,
    const int* __restrict__ rp,
    float* __restrict__ out)
{
    __shared__ int4 s_rp[Cn];
    if (threadIdx.x < Cn) {
        s_rp[threadIdx.x] = reinterpret_cast<const int4*>(rp)[threadIdx.x];
    }
    __syncthreads();

    const int gg = blockIdx.x * 64 + (threadIdx.x & 63); // global f4 group
    const int cq = threadIdx.x >> 6;                     // channel quarter

    // 4 coalesced u64 loads (512 B per wave each), all L2/L3-resident.
    const uint64_t r0 = ws[gg];
    const uint64_t r1 = ws[(size_t)GROUPS + gg];
    const uint64_t r2 = ws[(size_t)2 * GROUPS + gg];
    const uint64_t r3 = ws[(size_t)3 * GROUPS + gg];

    // Reassemble the four per-pixel 64-plane masks.
    const uint64_t m0 = ((r0      ) & 0xffffull)        | (((r1      ) & 0xffffull) << 16)
                      | (((r2      ) & 0xffffull) << 32) | (((r3      ) & 0xffffull) << 48);
    const uint64_t m1 = ((r0 >> 16) & 0xffffull)        | (((r1 >> 16) & 0xffffull) << 16)
                      | (((r2 >> 16) & 0xffffull) << 32) | (((r3 >> 16) & 0xffffull) << 48);
    const uint64_t m2 = ((r0 >> 32) & 0xffffull)        | (((r1 >> 32) & 0xffffull) << 16)
                      | (((r2 >> 32) & 0xffffull) << 32) | (((r3 >> 32) & 0xffffull) << 48);
    const uint64_t m3 = ((r0 >> 48) & 0xffffull)        | (((r1 >> 48) & 0xffffull) << 16)
                      | (((r2 >> 48) & 0xffffull) << 32) | (((r3 >> 48) & 0xffffull) << 48);

    const int b = gg >> 12;                 // 4096 groups per image
    const int pix = (gg & 4095) << 2;
    const int c0 = cq * 16;
    float* ob = out + (size_t)b * Cn * HW + (size_t)c0 * HW + pix;

    #pragma unroll
    for (int ci = 0; ci < 16; ++ci) {
        const int4 r = s_rp[c0 + ci];
        const unsigned i0 = (unsigned)r.x;
        const unsigned i1 = (unsigned)r.y;
        const unsigned i2 = (unsigned)r.z;
        const unsigned i3 = (unsigned)r.w;

        float4 o;
        o.x = (float)((unsigned)((m0 >> i0) & 1ull)
                    | ((unsigned)((m0 >> i1) & 1ull) << 1)
                    | ((unsigned)((m0 >> i2) & 1ull) << 2)
                    | ((unsigned)((m0 >> i3) & 1ull) << 3));
        o.y = (float)((unsigned)((m1 >> i0) & 1ull)
                    | ((unsigned)((m1 >> i1) & 1ull) << 1)
                    | ((unsigned)((m1 >> i2) & 1ull) << 2)
                    | ((unsigned)((m1 >> i3) & 1ull) << 3));
        o.z = (float)((unsigned)((m2 >> i0) & 1ull)
                    | ((unsigned)((m2 >> i1) & 1ull) << 1)
                    | ((unsigned)((m2 >> i2) & 1ull) << 2)
                    | ((unsigned)((m2 >> i3) & 1ull) << 3));
        o.w = (float)((unsigned)((m3 >> i0) & 1ull)
                    | ((unsigned)((m3 >> i1) & 1ull) << 1)
                    | ((unsigned)((m3 >> i2) & 1ull) << 2)
                    | ((unsigned)((m3 >> i3) & 1ull) << 3));

        *reinterpret_cast<float4*>(ob + (size_t)ci * HW) = o;
    }
}

extern "C" void kernel_launch(void* const* d_in, const int* in_sizes, int n_in,
                              void* d_out, int out_size, void* d_ws, size_t ws_size,
                              hipStream_t stream) {
    const float* x = (const float*)d_in[0];
    const int* rp = (const int*)d_in[1];
    float* out = (float*)d_out;
    uint64_t* ws = (uint64_t*)d_ws;         // needs 4*65536*8 B = 2 MiB

    constexpr int BLOCK = 256;
    rp_pack_p1<<<BLOCKS, BLOCK, 0, stream>>>(x, ws);
    rp_pack_p2<<<BLOCKS, BLOCK, 0, stream>>>(ws, rp, out);
}